// Round 1
// baseline (1713.876 us; speedup 1.0000x reference)
//
#include <hip/hip_runtime.h>
#include <cstdint>
#include <cstddef>

// Problem constants (match reference)
#define NIT    500
#define GAMMA_ 5.0f
#define CC_    1e-3f
#define KAPPA_ 2.0627128075074256f
#define PEN_   100.0f
#define LR_    0.01f

// d_ws layout: pbuf [128 b][2 dir][2 parity][100] f32 = 204800 B, then flags [256] int.
// TOTAL ~206 KB. r6/r14 post-mortem: both 617 KB layouts failed with garbage-neighbor
// signatures while every <=410 KB layout passed -> treat ws budget as ~512 KB hard.
#define PBUF_BYTES (128*2*2*100*4)
#define FLAG_COUNT 256

// Cross-WG primitives (r11/r13-proven): relaxed SYSTEM-scope atomic load/store ->
// coherence point, no cache-wide maintenance (r11: agent acq/rel wb/inv was a
// ~6us/iter floor), no RMW serialization (r12: RMW polls = HBM atomic storm).
#define VMFENCE() asm volatile("s_waitcnt vmcnt(0)" ::: "memory")
__device__ __forceinline__ float sysLoadF(float* p) {
  return __hip_atomic_load(p, __ATOMIC_RELAXED, __HIP_MEMORY_SCOPE_SYSTEM);
}
__device__ __forceinline__ void sysStoreF(float* p, float v) {
  __hip_atomic_store(p, v, __ATOMIC_RELAXED, __HIP_MEMORY_SCOPE_SYSTEM);
}
__device__ __forceinline__ int sysLoadI(int* p) {
  return __hip_atomic_load(p, __ATOMIC_RELAXED, __HIP_MEMORY_SCOPE_SYSTEM);
}
__device__ __forceinline__ void sysStoreI(int* p, int v) {
  __hip_atomic_store(p, v, __ATOMIC_RELAXED, __HIP_MEMORY_SCOPE_SYSTEM);
}
__device__ __forceinline__ int flagRead(int* p, int lane) {
  int f = 0;
  if (lane == 0) f = sysLoadI(p);
  return __builtin_amdgcn_readfirstlane(f);
}
// Intra-WG flag in LDS: workgroup-scope acq/rel = lgkm waits only, no cache ops.
__device__ __forceinline__ int ldsLoadAcq(int* p) {
  return __hip_atomic_load(p, __ATOMIC_ACQUIRE, __HIP_MEMORY_SCOPE_WORKGROUP);
}
__device__ __forceinline__ void ldsStoreRel(int* p, int v) {
  __hip_atomic_store(p, v, __ATOMIC_RELEASE, __HIP_MEMORY_SCOPE_WORKGROUP);
}

__device__ __forceinline__ float rdlane(float v, int lane) {
  return __int_as_float(__builtin_amdgcn_readlane(__float_as_int(v), lane));
}

// Wave64 sum via DPP, total broadcast from lane 63. Verified r5..r13.
__device__ __forceinline__ float wred64(float x) {
  int t;
  t = __builtin_amdgcn_update_dpp(0, __float_as_int(x), 0x111, 0xf, 0xf, true); x += __int_as_float(t);
  t = __builtin_amdgcn_update_dpp(0, __float_as_int(x), 0x112, 0xf, 0xf, true); x += __int_as_float(t);
  t = __builtin_amdgcn_update_dpp(0, __float_as_int(x), 0x114, 0xf, 0xf, true); x += __int_as_float(t);
  t = __builtin_amdgcn_update_dpp(0, __float_as_int(x), 0x118, 0xf, 0xf, true); x += __int_as_float(t);
  t = __builtin_amdgcn_update_dpp(0, __float_as_int(x), 0x142, 0xa, 0xf, true); x += __int_as_float(t);
  t = __builtin_amdgcn_update_dpp(0, __float_as_int(x), 0x143, 0xc, 0xf, true); x += __int_as_float(t);
  return rdlane(x, 63);
}

// Intra-WG LDS flag spin (uniform condition per wave). Guarded like all spins.
#define SPIN_LDS(PTR, TGT)                                                   \
  do {                                                                       \
    if (!dead) {                                                             \
      long guard_ = 0;                                                       \
      while (ldsLoadAcq(PTR) < (TGT)) {                                      \
        __builtin_amdgcn_s_sleep(1);                                         \
        if (++guard_ > (1L << 18)) { dead = true; break; }                   \
      }                                                                      \
    }                                                                        \
  } while (0)

// r13/r15 skeleton (256 WGs, one per (b,half), 6 heads x 2 waves; residency proven).
// Round-16 change: REMOVE both per-iteration __syncthreads. The barrier convoyed
// all 12 waves behind the slowest head's post (Michelot reset bursts = 600-1000cy
// for ONE head) and behind the boundary wave's vmcnt(0) publish drain. The true
// dep graph is per-head: matvec(k) needs own w^k; post(k) needs own y(k) and
// wbuf of j+-1 at iter k. Implemented with per-head LDS acq/rel flags
// (yflag[j], wflag[j]; same proven primitive as nflag) + ring-3 wbuf.
// Ring-3 safety: overwrite of slot p at post k+2 is gated by wflag[j+-1]>=k+2
// => neighbor finished post k+1 => its slot-p reads (post k) are done. ybuf/nbuf
// stay single-buffered: their overwrite at iter k+1 is gated by wflag[j]>=k+1,
// which A releases only after consuming them. Cross-WG ring-2 pbuf argument
// unchanged (their flag k+1 => their B consumed our slot-k data).
// All arithmetic is bitwise-identical to r15 -> absmax must stay 0.00012207.
// S constant-indexed only (r9: runtime index -> scratch spill -> 19.6 GB FETCH).
__global__ __launch_bounds__(768, 1) void mpo_solver(
    const float* __restrict__ mu, const float* __restrict__ L,
    const float* __restrict__ wprev, const float* __restrict__ climit,
    float* __restrict__ out, float* __restrict__ pbuf, int* __restrict__ flags)
{
  const int tid  = threadIdx.x;
  const int lane = tid & 63;
  const int wave = __builtin_amdgcn_readfirstlane(tid >> 6);  // 0..11
  const int j    = wave >> 1;       // local head 0..5
  const int sec  = wave & 1;        // 0 = rows 0-49 + post, 1 = rows 50-99
  const int bid  = blockIdx.x;
  const int b    = bid & 127;
  const int half = bid >> 7;        // 0: heads 0-5, 1: heads 6-11
  const int h    = half * 6 + j;    // global head
  const int bh   = b * 12 + h;

  __shared__ float wbuf[3][6][100];   // ring-3 w per head (slot m%3 holds w^m)
  __shared__ float ybuf[6][100];      // y rows 50-99 per head (B-wave's half)
  __shared__ float nbuf[100];         // delegated cross-WG neighbor w (one boundary head/WG)
  __shared__ int   nflag;             // nbuf holds iter-k data -> k
  __shared__ int   yflag[6];          // ybuf[j] holds iter-k data -> k
  __shared__ int   wflag[6];          // wbuf[(k)%3][j] holds w^k -> k

  const float* Lb = L + (size_t)bh * 10000;

  // ---------- Phase 0: SYRK. Lane owns row r of S = L L^T (fp32 regs/AGPRs). ----------
  float S[100];
#pragma unroll
  for (int c = 0; c < 100; ++c) S[c] = 0.f;
  const int r = sec * 50 + lane;      // valid row iff lane < 50
  if (lane < 50) {
#pragma unroll 1
    for (int mc = 0; mc < 25; ++mc) {
      float4 lr = *(const float4*)(Lb + r * 100 + mc * 4);
#pragma unroll
      for (int c = 0; c < 100; ++c) {
        const float* Lc = Lb + c * 100 + mc * 4;   // wave-uniform -> scalar loads
        S[c] = fmaf(lr.x, Lc[0], fmaf(lr.y, Lc[1], fmaf(lr.z, Lc[2], fmaf(lr.w, Lc[3], S[c]))));
      }
    }
  }

  const bool val1 = (lane < 36);
  float mu0 = mu[(size_t)bh * 100 + lane];
  float mu1 = val1 ? mu[(size_t)bh * 100 + 64 + lane] : 0.f;
  float wp0 = wprev[b * 100 + lane];
  float wp1 = val1 ? wprev[b * 100 + 64 + lane] : 0.f;
  float lim = climit[b];

  float w0 = wp0, w1 = wp1;           // post wave's iterate (n = lane, 64+lane)

  if (sec == 0) {
    wbuf[0][j][lane] = wp0;
    if (val1) wbuf[0][j][64 + lane] = wp1;
  }
  if (tid < 6) { yflag[tid] = -1; wflag[tid] = 0; }  // wflag=0: w^0 ready in slot 0
  if (tid == 6) nflag = 0;
  __syncthreads();                    // ONLY barrier in the kernel: init visibility

  const bool hasNext = (h < 11);
  const bool isPubL  = (half == 0) && (j == 5);  // boundary head: publishes 5, consumes 6
  const bool isPubH  = (half == 1) && (j == 0);  // boundary head: publishes 6, consumes 5
  const bool isBnd   = isPubL || isPubH;
  const int  flagPub = isPubL ? (b * 2 + 0) : (b * 2 + 1);
  const int  flagCon = isPubL ? (b * 2 + 1) : (b * 2 + 0);
  bool dead = false;
  float thp = -3.0e38f;               // warm Michelot seed; k=0 -> full support

  for (int k = 0; k < NIT; ++k) {
    const int p = k - (k / 3) * 3;    // k % 3 (compiler folds; keep cheap)

    // B gate: own w^k must be in wbuf[p][j] (A wrote it at post k-1 + released).
    // A needs no gate: it wrote its own wbuf slot (program order).
    if (sec == 1 && k > 0) SPIN_LDS(&wflag[j], k);

    // ---------- matvec y = S * w_k: wave-uniform ds_read_b128 broadcast ----------
    float yloc;
    {
      float a0 = 0.f, a1 = 0.f, a2 = 0.f, a3 = 0.f;
      const float* wrow = wbuf[p][j];
#pragma unroll
      for (int q = 0; q < 25; ++q) {
        float4 wq = *(const float4*)(wrow + q * 4);
        a0 = fmaf(wq.x, S[q * 4 + 0], a0);
        a1 = fmaf(wq.y, S[q * 4 + 1], a1);
        a2 = fmaf(wq.z, S[q * 4 + 2], a2);
        a3 = fmaf(wq.w, S[q * 4 + 3], a3);
      }
      yloc = (a0 + a2) + (a1 + a3);
    }

    if (sec == 1) {
      // ---------------- B wave: publish y-half, then delegated cross-read ----------------
      if (lane < 50) ybuf[j][50 + lane] = yloc;
      ldsStoreRel(&yflag[j], k);      // release covers the ybuf writes

      if (isBnd && k > 0) {
        // nbuf(k-1) already consumed: we passed wflag[j]>=k at loop top, which A
        // released only after reading nbuf(k-1).
        if (!dead) {
          long guard = 0;
          while (flagRead(&flags[flagCon], lane) < k) {
            __builtin_amdgcn_s_sleep(1);
            if (++guard > (1L << 18)) { dead = true; break; }
          }
        }
        // two-phase: data issued only after flag>=k observed (producer fenced
        // data before flag -> flag visible implies data visible)
        float* src = pbuf + ((size_t)flagCon * 2 + (k & 1)) * 100;
        nbuf[lane] = sysLoadF(&src[lane]);
        if (val1) nbuf[64 + lane] = sysLoadF(&src[64 + lane]);
        ldsStoreRel(&nflag, k);       // release covers the nbuf LDS writes
      }
    } else {
      // ---------------- A wave: post ----------------
      // ret needs no y -> compute before waiting on B (overlaps B's ybuf publish).
      float ret = wred64(fmaf(mu0, w0, mu1 * w1));

      SPIN_LDS(&yflag[j], k);
      float y0 = (lane < 50) ? yloc : ybuf[j][lane];
      float y1 = val1 ? ybuf[j][64 + lane] : 0.f;

      float s2  = wred64(fmaf(y0, w0, y1 * w1));
      float sigma = sqrtf(s2 + 1e-12f);
      float z     = KAPPA_ * sigma - ret - lim;
      float act   = (z > 0.f) ? 1.f : 0.f;
      float cY    = 2.f * GAMMA_ + act * (PEN_ * KAPPA_ / sigma);
      float cM    = -(1.f + act * PEN_);

      // neighbor w (iterate k exactly — Jacobi, matches reference)
      float wl0, wl1, wn0 = 0.f, wn1 = 0.f;
      if (j == 0) {
        if (half == 0 || k == 0) { wl0 = wp0; wl1 = wp1; }
        else {
          SPIN_LDS(&nflag, k);
          wl0 = nbuf[lane];
          wl1 = val1 ? nbuf[64 + lane] : 0.f;
        }
      } else {
        SPIN_LDS(&wflag[j - 1], k);
        wl0 = wbuf[p][j - 1][lane];
        wl1 = val1 ? wbuf[p][j - 1][64 + lane] : 0.f;
      }
      if (hasNext) {
        if (j == 5) {  // half==0 boundary: next is head 6 (delegated)
          if (k == 0) { wn0 = wp0; wn1 = wp1; }
          else {
            SPIN_LDS(&nflag, k);
            wn0 = nbuf[lane];
            wn1 = val1 ? nbuf[64 + lane] : 0.f;
          }
        } else {
          SPIN_LDS(&wflag[j + 1], k);
          wn0 = wbuf[p][j + 1][lane];
          wn1 = val1 ? wbuf[p][j + 1][64 + lane] : 0.f;
        }
      }

      float dw0 = w0 - wl0;
      float g0  = fmaf(cM, mu0, cY * y0) + CC_ * (dw0 * rsqrtf(fmaf(dw0, dw0, 1e-10f)));
      if (hasNext) { float dn0 = wn0 - w0; g0 -= CC_ * (dn0 * rsqrtf(fmaf(dn0, dn0, 1e-10f))); }
      float v0 = fmaf(-LR_, g0, w0);
      float v1 = 0.f;
      if (val1) {
        float dw1 = w1 - wl1;
        float g1  = fmaf(cM, mu1, cY * y1) + CC_ * (dw1 * rsqrtf(fmaf(dw1, dw1, 1e-10f)));
        if (hasNext) { float dn1 = wn1 - w1; g1 -= CC_ * (dn1 * rsqrtf(fmaf(dn1, dn1, 1e-10f))); }
        v1 = fmaf(-LR_, g1, w1);
      }

      // ---- Michelot projection, warm-started (r8/r10/r11/r13-verified numerics) ----
      float a1m = val1 ? 1.f : 0.f;
      float na0 = (v0 > thp) ? 1.f : 0.f;
      float na1 = (val1 && (v1 > thp)) ? 1.f : 0.f;
      float Ssum = wred64(na0 * v0 + na1 * v1);
      float Cnt  = wred64(na0 + na1);
      if (Cnt < 0.5f) { Ssum = wred64(v0 + a1m * v1); Cnt = 100.f; }
      float theta = (Ssum - 1.f) / Cnt;
      for (int it = 0; it < 112; ++it) {
        na0 = (v0 > theta) ? 1.f : 0.f;
        na1 = (val1 && (v1 > theta)) ? 1.f : 0.f;
        float ns = wred64(na0 * v0 + na1 * v1);
        float nc = wred64(na0 + na1);
        if (nc == Cnt && ns == Ssum) break;
        if (it == 7) {  // warm-start may cycle: reset to full support (monotone)
          ns = wred64(v0 + a1m * v1);
          nc = 100.f;
        }
        Ssum = ns; Cnt = nc;
        theta = (Ssum - 1.f) / Cnt;
      }
      thp = theta;
      w0 = fmaxf(v0 - theta, 0.f);
      w1 = val1 ? fmaxf(v1 - theta, 0.f) : 0.f;

      // Intra-WG release first (lgkm-only; lets B and neighbor heads proceed),
      // then the cross-WG publish with its vmcnt drain on THIS wave only.
      int pn = p + 1; if (pn == 3) pn = 0;
      wbuf[pn][j][lane] = w0;
      if (val1) wbuf[pn][j][64 + lane] = w1;
      ldsStoreRel(&wflag[j], k + 1);  // release covers wbuf writes AND nbuf/ybuf reads

      if (isBnd) {
        float* dst = pbuf + ((size_t)flagPub * 2 + ((k + 1) & 1)) * 100;
        sysStoreF(&dst[lane], w0);
        if (val1) sysStoreF(&dst[64 + lane], w1);
        VMFENCE();   // only this wave's 1-2 stores outstanding -> cheap
        if (lane == 0) sysStoreI(&flags[flagPub], k + 1);
      }
    }
  }

  if (sec == 0) {
    float* o = out + (size_t)bh * 100;
    o[lane] = w0;
    if (val1) o[64 + lane] = w1;
  }
}

extern "C" void kernel_launch(void* const* d_in, const int* in_sizes, int n_in,
                              void* d_out, int out_size, void* d_ws, size_t ws_size,
                              hipStream_t stream) {
  const float* mu = (const float*)d_in[0];
  const float* L  = (const float*)d_in[1];
  const float* wp = (const float*)d_in[2];
  const float* cl = (const float*)d_in[3];
  float* pbuf  = (float*)d_ws;
  int*   flags = (int*)((char*)d_ws + PBUF_BYTES);
  hipMemsetAsync(flags, 0, FLAG_COUNT * sizeof(int), stream);
  hipLaunchKernelGGL(mpo_solver, dim3(256), dim3(768), 0, stream,
                     mu, L, wp, cl, (float*)d_out, pbuf, flags);
}

// Round 2
// 1698.434 us; speedup vs baseline: 1.0091x; 1.0091x over previous
//
#include <hip/hip_runtime.h>
#include <cstdint>
#include <cstddef>

// Problem constants (match reference)
#define NIT    500
#define GAMMA_ 5.0f
#define CC_    1e-3f
#define KAPPA_ 2.0627128075074256f
#define PEN_   100.0f
#define LR_    0.01f

// d_ws layout: pbuf [128 b][2 dir][2 parity][100] f32 = 204800 B, then flags [256] int.
// TOTAL ~206 KB. r6/r14 post-mortem: both 617 KB layouts failed with garbage-neighbor
// signatures while every <=410 KB layout passed -> treat ws budget as ~512 KB hard.
#define PBUF_BYTES (128*2*2*100*4)
#define FLAG_COUNT 256

// Cross-WG primitives (r11/r13-proven): relaxed SYSTEM-scope atomic load/store ->
// coherence point, no cache-wide maintenance (r11: agent acq/rel wb/inv was a
// ~6us/iter floor), no RMW serialization (r12: RMW polls = HBM atomic storm).
#define VMFENCE() asm volatile("s_waitcnt vmcnt(0)" ::: "memory")
__device__ __forceinline__ float sysLoadF(float* p) {
  return __hip_atomic_load(p, __ATOMIC_RELAXED, __HIP_MEMORY_SCOPE_SYSTEM);
}
__device__ __forceinline__ void sysStoreF(float* p, float v) {
  __hip_atomic_store(p, v, __ATOMIC_RELAXED, __HIP_MEMORY_SCOPE_SYSTEM);
}
__device__ __forceinline__ int sysLoadI(int* p) {
  return __hip_atomic_load(p, __ATOMIC_RELAXED, __HIP_MEMORY_SCOPE_SYSTEM);
}
__device__ __forceinline__ void sysStoreI(int* p, int v) {
  __hip_atomic_store(p, v, __ATOMIC_RELAXED, __HIP_MEMORY_SCOPE_SYSTEM);
}
__device__ __forceinline__ int flagRead(int* p, int lane) {
  int f = 0;
  if (lane == 0) f = sysLoadI(p);
  return __builtin_amdgcn_readfirstlane(f);
}
// Intra-WG flag in LDS: workgroup-scope acq/rel = lgkm waits only, no cache ops.
__device__ __forceinline__ int ldsLoadAcq(int* p) {
  return __hip_atomic_load(p, __ATOMIC_ACQUIRE, __HIP_MEMORY_SCOPE_WORKGROUP);
}
__device__ __forceinline__ void ldsStoreRel(int* p, int v) {
  __hip_atomic_store(p, v, __ATOMIC_RELEASE, __HIP_MEMORY_SCOPE_WORKGROUP);
}

__device__ __forceinline__ float rdlane(float v, int lane) {
  return __int_as_float(__builtin_amdgcn_readlane(__float_as_int(v), lane));
}

// Wave64 sum via DPP, total broadcast from lane 63. Verified r5..r13.
__device__ __forceinline__ float wred64(float x) {
  int t;
  t = __builtin_amdgcn_update_dpp(0, __float_as_int(x), 0x111, 0xf, 0xf, true); x += __int_as_float(t);
  t = __builtin_amdgcn_update_dpp(0, __float_as_int(x), 0x112, 0xf, 0xf, true); x += __int_as_float(t);
  t = __builtin_amdgcn_update_dpp(0, __float_as_int(x), 0x114, 0xf, 0xf, true); x += __int_as_float(t);
  t = __builtin_amdgcn_update_dpp(0, __float_as_int(x), 0x118, 0xf, 0xf, true); x += __int_as_float(t);
  t = __builtin_amdgcn_update_dpp(0, __float_as_int(x), 0x142, 0xa, 0xf, true); x += __int_as_float(t);
  t = __builtin_amdgcn_update_dpp(0, __float_as_int(x), 0x143, 0xc, 0xf, true); x += __int_as_float(t);
  return rdlane(x, 63);
}

// r15 skeleton restored (best measured: 1651us; 2 barriers/iter). r16 post-mortem:
// replacing barriers with per-head LDS acq/rel flags REGRESSED (+4%, VALUBusy 40->45.5)
// -> each acquire gate is a ~120cy LDS round trip and A's path has ~4 of them;
// the 12-wave rendezvous is cheaper. Sync structure is NOT the bottleneck.
//
// Round-17 change (scheduling only, zero semantic delta): SIMD-balanced wave remap.
// HW places wave w of a WG on SIMD w%4. Old decode (j=wave>>1, sec=wave&1) put all
// 6 post-heavy A-waves on SIMDs {0,2} and all post-idle B-waves on SIMDs {1,3}:
// during the serial post chain, two SIMDs juggle 3 heavy waves each while two idle.
// New decode: waves 0-5 = A of heads 0-5, waves 6-11 = B -> A-per-SIMD {2,2,1,1}.
// All arithmetic bitwise-identical -> absmax must stay 0.00012207.
// S constant-indexed only (r9: runtime index -> scratch spill -> 19.6 GB FETCH).
__global__ __launch_bounds__(768, 1) void mpo_solver(
    const float* __restrict__ mu, const float* __restrict__ L,
    const float* __restrict__ wprev, const float* __restrict__ climit,
    float* __restrict__ out, float* __restrict__ pbuf, int* __restrict__ flags)
{
  const int tid  = threadIdx.x;
  const int lane = tid & 63;
  const int wave = __builtin_amdgcn_readfirstlane(tid >> 6);  // 0..11
  const int sec  = (wave >= 6) ? 1 : 0;  // 0 = A (rows 0-49 + post), 1 = B (rows 50-99)
  const int j    = sec ? (wave - 6) : wave;   // local head 0..5
  const int bid  = blockIdx.x;
  const int b    = bid & 127;
  const int half = bid >> 7;        // 0: heads 0-5, 1: heads 6-11
  const int h    = half * 6 + j;    // global head
  const int bh   = b * 12 + h;

  __shared__ float wbuf[2][6][100];   // double-buffered w per head
  __shared__ float ybuf[6][100];      // y rows 50-99 per head (B-wave's half)
  __shared__ float nbuf[100];         // delegated cross-WG neighbor w (one boundary head/WG)
  __shared__ int   nflag;             // nbuf holds iter-k data -> k

  const float* Lb = L + (size_t)bh * 10000;

  // ---------- Phase 0: SYRK. Lane owns row r of S = L L^T (fp32 regs/AGPRs). ----------
  float S[100];
#pragma unroll
  for (int c = 0; c < 100; ++c) S[c] = 0.f;
  const int r = sec * 50 + lane;      // valid row iff lane < 50
  if (lane < 50) {
#pragma unroll 1
    for (int mc = 0; mc < 25; ++mc) {
      float4 lr = *(const float4*)(Lb + r * 100 + mc * 4);
#pragma unroll
      for (int c = 0; c < 100; ++c) {
        const float* Lc = Lb + c * 100 + mc * 4;   // wave-uniform -> scalar loads
        S[c] = fmaf(lr.x, Lc[0], fmaf(lr.y, Lc[1], fmaf(lr.z, Lc[2], fmaf(lr.w, Lc[3], S[c]))));
      }
    }
  }

  const bool val1 = (lane < 36);
  float mu0 = mu[(size_t)bh * 100 + lane];
  float mu1 = val1 ? mu[(size_t)bh * 100 + 64 + lane] : 0.f;
  float wp0 = wprev[b * 100 + lane];
  float wp1 = val1 ? wprev[b * 100 + 64 + lane] : 0.f;
  float lim = climit[b];

  float w0 = wp0, w1 = wp1;           // post wave's iterate (n = lane, 64+lane)

  if (sec == 0) {
    wbuf[0][j][lane] = wp0;
    if (val1) wbuf[0][j][64 + lane] = wp1;
  }
  if (tid == 0) nflag = 0;
  __syncthreads();

  const bool hasNext = (h < 11);
  const bool isPubL  = (half == 0) && (j == 5);  // boundary head: publishes 5, consumes 6
  const bool isPubH  = (half == 1) && (j == 0);  // boundary head: publishes 6, consumes 5
  const bool isBnd   = isPubL || isPubH;
  const int  flagPub = isPubL ? (b * 2 + 0) : (b * 2 + 1);
  const int  flagCon = isPubL ? (b * 2 + 1) : (b * 2 + 0);
  bool dead = false;
  float thp = -3.0e38f;               // warm Michelot seed; k=0 -> full support

  for (int k = 0; k < NIT; ++k) {
    const int p = k & 1;

    // ---------- matvec y = S * w_k: wave-uniform ds_read_b128 broadcast ----------
    float yloc;
    {
      float a0 = 0.f, a1 = 0.f, a2 = 0.f, a3 = 0.f;
      const float* wrow = wbuf[p][j];
#pragma unroll
      for (int q = 0; q < 25; ++q) {
        float4 wq = *(const float4*)(wrow + q * 4);
        a0 = fmaf(wq.x, S[q * 4 + 0], a0);
        a1 = fmaf(wq.y, S[q * 4 + 1], a1);
        a2 = fmaf(wq.z, S[q * 4 + 2], a2);
        a3 = fmaf(wq.w, S[q * 4 + 3], a3);
      }
      yloc = (a0 + a2) + (a1 + a3);
      if (sec == 1 && lane < 50) ybuf[j][50 + lane] = yloc;  // only B publishes its half
    }
    __syncthreads();

    // ================= post window =================
    if (sec == 1) {
      // ---- B wave of the boundary head: delegated cross-WG read (otherwise idle) ----
      if (isBnd && k > 0) {
        if (!dead) {
          long guard = 0;
          while (flagRead(&flags[flagCon], lane) < k) {
            __builtin_amdgcn_s_sleep(1);
            if (++guard > (1L << 18)) { dead = true; break; }
          }
        }
        // two-phase: data issued only after flag>=k observed (producer fenced
        // data before flag -> flag visible implies data visible)
        float* src = pbuf + ((size_t)flagCon * 2 + (k & 1)) * 100;
        nbuf[lane] = sysLoadF(&src[lane]);
        if (val1) nbuf[64 + lane] = sysLoadF(&src[64 + lane]);
        if (lane == 0) { /* LDS release after LDS writes */ }
        ldsStoreRel(&nflag, k);   // release covers the nbuf LDS writes
      }
    } else {
      // ---------------- A wave: post ----------------
      float y0 = (lane < 50) ? yloc : ybuf[j][lane];
      float y1 = val1 ? ybuf[j][64 + lane] : 0.f;

      float ret = wred64(fmaf(mu0, w0, mu1 * w1));
      float s2  = wred64(fmaf(y0, w0, y1 * w1));
      float sigma = sqrtf(s2 + 1e-12f);
      float z     = KAPPA_ * sigma - ret - lim;
      float act   = (z > 0.f) ? 1.f : 0.f;
      float cY    = 2.f * GAMMA_ + act * (PEN_ * KAPPA_ / sigma);
      float cM    = -(1.f + act * PEN_);

      // neighbor w (iterate k exactly — Jacobi, matches reference)
      float wl0, wl1, wn0 = 0.f, wn1 = 0.f;
      if (j == 0) {
        if (half == 0 || k == 0) { wl0 = wp0; wl1 = wp1; }
        else {
          if (!dead) {
            long guard = 0;
            while (ldsLoadAcq(&nflag) < k) {
              __builtin_amdgcn_s_sleep(1);
              if (++guard > (1L << 18)) { dead = true; break; }
            }
          }
          wl0 = nbuf[lane];
          wl1 = val1 ? nbuf[64 + lane] : 0.f;
        }
      } else { wl0 = wbuf[p][j - 1][lane]; wl1 = val1 ? wbuf[p][j - 1][64 + lane] : 0.f; }
      if (hasNext) {
        if (j == 5) {  // half==0 boundary: next is head 6 (delegated)
          if (k == 0) { wn0 = wp0; wn1 = wp1; }
          else {
            if (!dead) {
              long guard = 0;
              while (ldsLoadAcq(&nflag) < k) {
                __builtin_amdgcn_s_sleep(1);
                if (++guard > (1L << 18)) { dead = true; break; }
              }
            }
            wn0 = nbuf[lane];
            wn1 = val1 ? nbuf[64 + lane] : 0.f;
          }
        } else { wn0 = wbuf[p][j + 1][lane]; wn1 = val1 ? wbuf[p][j + 1][64 + lane] : 0.f; }
      }

      float dw0 = w0 - wl0;
      float g0  = fmaf(cM, mu0, cY * y0) + CC_ * (dw0 * rsqrtf(fmaf(dw0, dw0, 1e-10f)));
      if (hasNext) { float dn0 = wn0 - w0; g0 -= CC_ * (dn0 * rsqrtf(fmaf(dn0, dn0, 1e-10f))); }
      float v0 = fmaf(-LR_, g0, w0);
      float v1 = 0.f;
      if (val1) {
        float dw1 = w1 - wl1;
        float g1  = fmaf(cM, mu1, cY * y1) + CC_ * (dw1 * rsqrtf(fmaf(dw1, dw1, 1e-10f)));
        if (hasNext) { float dn1 = wn1 - w1; g1 -= CC_ * (dn1 * rsqrtf(fmaf(dn1, dn1, 1e-10f))); }
        v1 = fmaf(-LR_, g1, w1);
      }

      // ---- Michelot projection, warm-started (r8/r10/r11/r13-verified numerics) ----
      float a1m = val1 ? 1.f : 0.f;
      float na0 = (v0 > thp) ? 1.f : 0.f;
      float na1 = (val1 && (v1 > thp)) ? 1.f : 0.f;
      float Ssum = wred64(na0 * v0 + na1 * v1);
      float Cnt  = wred64(na0 + na1);
      if (Cnt < 0.5f) { Ssum = wred64(v0 + a1m * v1); Cnt = 100.f; }
      float theta = (Ssum - 1.f) / Cnt;
      for (int it = 0; it < 112; ++it) {
        na0 = (v0 > theta) ? 1.f : 0.f;
        na1 = (val1 && (v1 > theta)) ? 1.f : 0.f;
        float ns = wred64(na0 * v0 + na1 * v1);
        float nc = wred64(na0 + na1);
        if (nc == Cnt && ns == Ssum) break;
        if (it == 7) {  // warm-start may cycle: reset to full support (monotone)
          ns = wred64(v0 + a1m * v1);
          nc = 100.f;
        }
        Ssum = ns; Cnt = nc;
        theta = (Ssum - 1.f) / Cnt;
      }
      thp = theta;
      w0 = fmaxf(v0 - theta, 0.f);
      w1 = val1 ? fmaxf(v1 - theta, 0.f) : 0.f;

      wbuf[1 - p][j][lane] = w0;
      if (val1) wbuf[1 - p][j][64 + lane] = w1;

      // ---- IMMEDIATE cross-WG publish: data, fence, flag (boundary A only) ----
      if (isBnd) {
        float* dst = pbuf + ((size_t)flagPub * 2 + ((k + 1) & 1)) * 100;
        sysStoreF(&dst[lane], w0);
        if (val1) sysStoreF(&dst[64 + lane], w1);
        VMFENCE();   // only this wave's 1-2 stores outstanding -> cheap
        if (lane == 0) sysStoreI(&flags[flagPub], k + 1);
      }
    }
    __syncthreads();
  }

  if (sec == 0) {
    float* o = out + (size_t)bh * 100;
    o[lane] = w0;
    if (val1) o[64 + lane] = w1;
  }
}

extern "C" void kernel_launch(void* const* d_in, const int* in_sizes, int n_in,
                              void* d_out, int out_size, void* d_ws, size_t ws_size,
                              hipStream_t stream) {
  const float* mu = (const float*)d_in[0];
  const float* L  = (const float*)d_in[1];
  const float* wp = (const float*)d_in[2];
  const float* cl = (const float*)d_in[3];
  float* pbuf  = (float*)d_ws;
  int*   flags = (int*)((char*)d_ws + PBUF_BYTES);
  hipMemsetAsync(flags, 0, FLAG_COUNT * sizeof(int), stream);
  hipLaunchKernelGGL(mpo_solver, dim3(256), dim3(768), 0, stream,
                     mu, L, wp, cl, (float*)d_out, pbuf, flags);
}